// Round 1
// baseline (2025.909 us; speedup 1.0000x reference)
//
#include <hip/hip_runtime.h>
#include <cstdint>

// ElmanRNN: B=64, T=1024, I=H=256, fp32.
//   layer: xp = X @ W_ih^T + b ; h_t = tanh(xp_t + h_{t-1} @ W_hh^T)
// Plan: GEMM0 (xp0 -> ws) ; scan0 (y0 -> d_out) ; GEMM1 (xp1 -> ws) ; scan1 (-> d_out)
// Requires ws_size >= 64 MB (M*H*4 bytes).

#define HDIM 256
#define TLEN 1024
#define BATCH 64

// ---------------------------------------------------------------------------
// Input-projection GEMM: C[m][n] = bias[n] + sum_k X[m][k] * W[n][k]
// M = 65536, N = K = 256.  BLK_M=128, BLK_N=64, BLK_K=16, 256 threads, 8x4 microtile.
// ---------------------------------------------------------------------------
__global__ __launch_bounds__(256) void proj_gemm(
    const float* __restrict__ X,
    const float* __restrict__ W,
    const float* __restrict__ bias,
    float* __restrict__ C, int M)
{
    __shared__ __align__(16) float Ast[16][136];  // [k][m], pad 128->136 (16B-safe rows)
    __shared__ __align__(16) float Bst[16][68];   // [k][n], pad 64->68

    const int tid = threadIdx.x;
    const int tx  = tid & 15;     // n-dir, 4 cols each
    const int ty  = tid >> 4;     // m-dir, 8 rows each
    const int m0  = blockIdx.x * 128;
    const int n0  = blockIdx.y * 64;

    float acc[8][4];
#pragma unroll
    for (int i = 0; i < 8; ++i)
#pragma unroll
        for (int j = 0; j < 4; ++j) acc[i][j] = 0.f;

    const int ar = tid >> 1;          // 0..127 : A row
    const int ah = (tid & 1) * 8;     // k offset 0 / 8
    const int bn = tid >> 2;          // 0..63  : B row (n)
    const int bg = (tid & 3) * 4;     // k offset 0/4/8/12

    for (int kc = 0; kc < 16; ++kc) {
        const int k0 = kc * 16;
        const float4 av0 = *reinterpret_cast<const float4*>(&X[(size_t)(m0 + ar) * HDIM + k0 + ah]);
        const float4 av1 = *reinterpret_cast<const float4*>(&X[(size_t)(m0 + ar) * HDIM + k0 + ah + 4]);
        const float4 bv  = *reinterpret_cast<const float4*>(&W[(size_t)(n0 + bn) * HDIM + k0 + bg]);
        __syncthreads();              // previous iter's readers done
        Ast[ah + 0][ar] = av0.x; Ast[ah + 1][ar] = av0.y;
        Ast[ah + 2][ar] = av0.z; Ast[ah + 3][ar] = av0.w;
        Ast[ah + 4][ar] = av1.x; Ast[ah + 5][ar] = av1.y;
        Ast[ah + 6][ar] = av1.z; Ast[ah + 7][ar] = av1.w;
        Bst[bg + 0][bn] = bv.x;  Bst[bg + 1][bn] = bv.y;
        Bst[bg + 2][bn] = bv.z;  Bst[bg + 3][bn] = bv.w;
        __syncthreads();
#pragma unroll
        for (int kk = 0; kk < 16; ++kk) {
            const float4 a0 = *reinterpret_cast<const float4*>(&Ast[kk][ty * 8]);
            const float4 a1 = *reinterpret_cast<const float4*>(&Ast[kk][ty * 8 + 4]);
            const float4 b4 = *reinterpret_cast<const float4*>(&Bst[kk][tx * 4]);
            const float av[8] = {a0.x, a0.y, a0.z, a0.w, a1.x, a1.y, a1.z, a1.w};
            const float bb[4] = {b4.x, b4.y, b4.z, b4.w};
#pragma unroll
            for (int i = 0; i < 8; ++i)
#pragma unroll
                for (int j = 0; j < 4; ++j)
                    acc[i][j] = fmaf(av[i], bb[j], acc[i][j]);
        }
    }

    const float4 bias4 = *reinterpret_cast<const float4*>(&bias[n0 + tx * 4]);
    const float bb[4] = {bias4.x, bias4.y, bias4.z, bias4.w};
#pragma unroll
    for (int i = 0; i < 8; ++i) {
        float4 o;
        o.x = acc[i][0] + bb[0];
        o.y = acc[i][1] + bb[1];
        o.z = acc[i][2] + bb[2];
        o.w = acc[i][3] + bb[3];
        *reinterpret_cast<float4*>(&C[(size_t)(m0 + ty * 8 + i) * HDIM + n0 + tx * 4]) = o;
    }
}

// ---------------------------------------------------------------------------
// Recurrent scan: one block per batch element, 1024 threads.
//   thread (q, j): q = tid>>8 (K-quarter), j = tid&255 (output index)
//   W_hh[j][q*64 .. q*64+63] held in registers (16 float4 = 64 VGPR).
//   h broadcast via LDS; 4-way partial reduction in LDS; two barriers/step.
// ---------------------------------------------------------------------------
__device__ __forceinline__ float fast_tanh(float x)
{
    const float xc = fminf(fmaxf(x, -15.f), 15.f);
    const float e  = __expf(2.f * xc);
    return (e - 1.f) / (e + 1.f);
}

__global__ __launch_bounds__(1024) void elman_scan(
    const float* __restrict__ xp,   // [B, T, H]
    const float* __restrict__ Whh,  // [H, H]
    float* __restrict__ y,          // [B, T, H]
    int T)
{
    const int b   = blockIdx.x;
    const int tid = threadIdx.x;
    const int j   = tid & 255;
    const int q   = tid >> 8;

    float4 w[16];
    const float4* wp = reinterpret_cast<const float4*>(Whh + (size_t)j * HDIM + q * 64);
#pragma unroll
    for (int c = 0; c < 16; ++c) w[c] = wp[c];

    __shared__ __align__(16) float hs[HDIM];
    __shared__ float red[3][HDIM];
    __shared__ float xpb[2][HDIM];

    const float* xrow = xp + (size_t)b * T * HDIM;
    float*       yrow = y  + (size_t)b * T * HDIM;

    if (q == 0) {
        hs[j] = 0.f;
        xpb[0][j] = xrow[j];
    }
    __syncthreads();

    for (int t = 0; t < T; ++t) {
        // ---- partial dot over this group's K-quarter (broadcast LDS reads) ----
        const float4* h4 = reinterpret_cast<const float4*>(&hs[q * 64]);
        float s0 = 0.f, s1 = 0.f, s2 = 0.f, s3 = 0.f;
#pragma unroll
        for (int c = 0; c < 16; c += 4) {
            const float4 h0 = h4[c + 0];
            const float4 h1 = h4[c + 1];
            const float4 h2 = h4[c + 2];
            const float4 h3 = h4[c + 3];
            s0 = fmaf(w[c + 0].x, h0.x, s0); s0 = fmaf(w[c + 0].y, h0.y, s0);
            s0 = fmaf(w[c + 0].z, h0.z, s0); s0 = fmaf(w[c + 0].w, h0.w, s0);
            s1 = fmaf(w[c + 1].x, h1.x, s1); s1 = fmaf(w[c + 1].y, h1.y, s1);
            s1 = fmaf(w[c + 1].z, h1.z, s1); s1 = fmaf(w[c + 1].w, h1.w, s1);
            s2 = fmaf(w[c + 2].x, h2.x, s2); s2 = fmaf(w[c + 2].y, h2.y, s2);
            s2 = fmaf(w[c + 2].z, h2.z, s2); s2 = fmaf(w[c + 2].w, h2.w, s2);
            s3 = fmaf(w[c + 3].x, h3.x, s3); s3 = fmaf(w[c + 3].y, h3.y, s3);
            s3 = fmaf(w[c + 3].z, h3.z, s3); s3 = fmaf(w[c + 3].w, h3.w, s3);
        }
        const float s = (s0 + s1) + (s2 + s3);

        if (q) red[q - 1][j] = s;
        __syncthreads();

        if (q == 0) {
            const float tot = s + red[0][j] + red[1][j] + red[2][j] + xpb[t & 1][j];
            const float hn  = fast_tanh(tot);
            hs[j] = hn;
            yrow[(size_t)t * HDIM + j] = hn;
        } else if (q == 1) {
            if (t + 1 < T) xpb[(t + 1) & 1][j] = xrow[(size_t)(t + 1) * HDIM + j];
        }
        __syncthreads();
    }
}

// ---------------------------------------------------------------------------
extern "C" void kernel_launch(void* const* d_in, const int* in_sizes, int n_in,
                              void* d_out, int out_size, void* d_ws, size_t ws_size,
                              hipStream_t stream)
{
    const float* x     = (const float*)d_in[0];
    const float* W_ih0 = (const float*)d_in[1];
    const float* b_ih0 = (const float*)d_in[2];
    const float* W_hh0 = (const float*)d_in[3];
    const float* W_ih1 = (const float*)d_in[4];
    const float* b_ih1 = (const float*)d_in[5];
    const float* W_hh1 = (const float*)d_in[6];

    float* out = (float*)d_out;
    float* xp  = (float*)d_ws;          // needs 64 MB

    const int M = BATCH * TLEN;
    dim3 ggrid(M / 128, HDIM / 64);

    proj_gemm<<<ggrid, 256, 0, stream>>>(x,   W_ih0, b_ih0, xp, M);
    elman_scan<<<BATCH, 1024, 0, stream>>>(xp, W_hh0, out, TLEN);
    proj_gemm<<<ggrid, 256, 0, stream>>>(out, W_ih1, b_ih1, xp, M);
    elman_scan<<<BATCH, 1024, 0, stream>>>(xp, W_hh1, out, TLEN);
}